// Round 4
// baseline (383.949 us; speedup 1.0000x reference)
//
#include <hip/hip_runtime.h>
#include <math.h>

// VIN forward on MI355X — single fused kernel.
// Sizes: N=128, H=W=64, CH_I=2, CH_H=150, CH_Q=10, N_ACT=8, VInum=36.
//
// R3 -> R4 change (single variable):
//  * __attribute__((amdgpu_waves_per_eu(4,4))) + amdgpu_flat_work_group_size:
//    R3's __launch_bounds__(1024,4) only set a MINIMUM occupancy (VGPR cap
//    128); the backend still TARGETED 8 waves/EU = 64-VGPR budget
//    (VGPR_Count=64 observed) and met it by re-issuing LDS reads per use
//    instead of keeping vwin/Rsw live -> the K-loop is LDS-issue bound
//    (~17K cy/iter of non-VALU wall). Occupancy is LDS-bound at 1 WG/CU =
//    4 waves/EU regardless, so pinning waves_per_eu to exactly 4 gives the
//    allocator the full 128-reg budget with zero occupancy cost.

#define XROW 69
#define VROW 67
#define VSTR (66 * VROW)          // 4422 floats per v buffer

__global__ void
__attribute__((amdgpu_flat_work_group_size(1024, 1024)))
__attribute__((amdgpu_waves_per_eu(4, 4)))
vin_kernel(const float* __restrict__ x,
                const int* __restrict__ S1,
                const int* __restrict__ S2,
                const int* __restrict__ VInum,
                const float* __restrict__ w0,
                const float* __restrict__ b0,
                const float* __restrict__ w_r,
                const float* __restrict__ w_q,
                const float* __restrict__ w_sw,
                const float* __restrict__ w_sw2,
                const float* __restrict__ w_dense,
                float* __restrict__ out) {
    const int b = blockIdx.x;
    const int t = threadIdx.x;

    __shared__ float xs0[68 * XROW];     // x channel 0, [y+2][x+2], 2-halo of zeros
    __shared__ float xs1[68 * XROW];     // x channel 1
    __shared__ float rs[66 * VROW];      // r with 1-halo of zeros
    __shared__ float vpool[2 * VSTR];    // v double buffer, 1-halo of zeros
    __shared__ float wtmp[840];          // W5 partials [0..749], B partials [750..839]
    __shared__ float wfin[60];           // W5[50], B[9], Btot
    __shared__ float qsel[10];

    // ---- zero LDS (halos must be 0) ----
    for (int i = t; i < 68 * XROW; i += 1024) { xs0[i] = 0.f; xs1[i] = 0.f; }
    for (int i = t; i < 66 * VROW; i += 1024) rs[i] = 0.f;
    for (int i = t; i < 2 * VSTR; i += 1024) vpool[i] = 0.f;
    __syncthreads();

    const int row = t >> 4;          // 0..63
    const int cb  = (t & 15) << 2;   // 0,4,...,60

    // ---- stage x into split planes ----
    {
        const float* xb = x + (size_t)b * 64 * 64 * 2;
        #pragma unroll
        for (int p = 0; p < 4; ++p) {
            int xx = cb + p;
            float2 v2 = *(const float2*)(xb + (row * 64 + xx) * 2);
            xs0[(row + 2) * XROW + (xx + 2)] = v2.x;
            xs1[(row + 2) * XROW + (xx + 2)] = v2.y;
        }
    }
    // ---- W5 compose partials: 50 entries x 15 channel-chunks ----
    if (t < 750) {
        int e2 = t / 15, pi = t - e2 * 15;
        int e = e2 >> 1, ci = e2 & 1;
        int ey = e / 5 - 2, ex = e % 5 - 2;
        int c0 = pi * 10;
        float s = 0.f;
        for (int dqy = -1; dqy <= 1; ++dqy)
            for (int dqx = -1; dqx <= 1; ++dqx) {
                int dsy = ey - dqy, dsx = ex - dqx;
                if (dsy < -1 || dsy > 1 || dsx < -1 || dsx > 1) continue;
                const float* wr = w_r + ((dqy + 1) * 3 + (dqx + 1)) * 150;
                const float* wp = w0 + (((dsy + 1) * 3 + (dsx + 1)) * 2 + ci) * 150;
                for (int c = c0; c < c0 + 10; ++c) s += wr[c] * wp[c];
            }
        wtmp[t] = s;
    } else if (t >= 768 && t < 858) {
        int j = t - 768;
        int d = j / 10, pi = j - d * 10, c0 = pi * 15;
        float s = 0.f;
        for (int c = c0; c < c0 + 15; ++c) s += w_r[d * 150 + c] * b0[c];
        wtmp[750 + j] = s;
    }
    __syncthreads();
    if (t < 50) {
        float s = 0.f;
        for (int i = 0; i < 15; ++i) s += wtmp[t * 15 + i];
        wfin[t] = s;
    } else if (t < 59) {
        int d = t - 50;
        float s = 0.f;
        for (int i = 0; i < 10; ++i) s += wtmp[750 + d * 10 + i];
        wfin[t] = s;
    } else if (t == 59) {
        float s = 0.f;
        for (int j = 0; j < 90; ++j) s += wtmp[750 + j];
        wfin[59] = s;
    }
    __syncthreads();

    // ---- r interior via composed 5x5 conv (split planes, conflict-free) ----
    {
        float W5a[25], W5b[25];
        #pragma unroll
        for (int e = 0; e < 25; ++e) { W5a[e] = wfin[e * 2]; W5b[e] = wfin[e * 2 + 1]; }
        float Btot = wfin[59];
        #pragma unroll
        for (int p = 0; p < 4; ++p) {
            int xx = cb + p;
            float acc = Btot;
            #pragma unroll
            for (int ey = 0; ey < 5; ++ey)
                #pragma unroll
                for (int ex = 0; ex < 5; ++ex) {
                    int xi = (row + ey) * XROW + (xx + ex);
                    acc = fmaf(xs0[xi], W5a[ey * 5 + ex], acc);
                    acc = fmaf(xs1[xi], W5b[ey * 5 + ex], acc);
                }
            rs[(row + 1) * VROW + (xx + 1)] = acc;
        }
    }
    __syncthreads();

    // ---- border fix: subtract virtual-h contributions from 260 outside-q ----
    if (t < 780) {
        int qi = t / 3, ch = t - qi * 3;
        int qy, qx;
        if (qi < 66)       { qy = -1; qx = qi - 1; }
        else if (qi < 132) { qy = 64; qx = qi - 67; }
        else if (qi < 196) { qx = -1; qy = qi - 132; }
        else               { qx = 64; qy = qi - 196; }
        float sdq[9];
        #pragma unroll
        for (int d = 0; d < 9; ++d) sdq[d] = 0.f;
        int c0 = ch * 50;
        for (int c = c0; c < c0 + 50; ++c) {
            float hc = 0.f;
            #pragma unroll
            for (int ky = 0; ky < 3; ++ky)
                #pragma unroll
                for (int kx = 0; kx < 3; ++kx) {
                    int xi = (qy + ky + 1) * XROW + (qx + kx + 1);
                    const float* wp = &w0[((ky * 3 + kx) * 2) * 150 + c];
                    hc = fmaf(xs0[xi], wp[0], hc);
                    hc = fmaf(xs1[xi], wp[150], hc);
                }
            #pragma unroll
            for (int d = 0; d < 9; ++d) sdq[d] = fmaf(w_r[d * 150 + c], hc, sdq[d]);
        }
        #pragma unroll
        for (int d = 0; d < 9; ++d) {
            int dy = d / 3 - 1, dx = d % 3 - 1;
            int py = qy - dy, px = qx - dx;
            if (py >= 0 && py < 64 && px >= 0 && px < 64) {
                float corr = sdq[d] + (ch == 0 ? wfin[50 + d] : 0.f);
                atomicAdd(&rs[(py + 1) * VROW + (px + 1)], -corr);
            }
        }
    }
    __syncthreads();

    const int K = VInum[0];

    // ---- Rsw precompute (loop-invariant r-part of w_sw conv) + first step (w_q) ----
    float Rsw[4][10];
    {
        float rwin[3][6];
        #pragma unroll
        for (int i = 0; i < 3; ++i) {
            const float* rp = &rs[(row + i) * VROW + cb];
            #pragma unroll
            for (int j = 0; j < 6; ++j) rwin[i][j] = rp[j];
        }
        float vmax[4];
        #pragma unroll
        for (int a = 0; a < 10; ++a) {
            #pragma unroll
            for (int p = 0; p < 4; ++p) {
                float accR = 0.f, accQ = 0.f;
                #pragma unroll
                for (int d = 0; d < 9; ++d) {
                    float rv = rwin[d / 3][p + d % 3];
                    accR = fmaf(w_sw[d * 20 + a], rv, accR);
                    accQ = fmaf(w_q[d * 20 + a],  rv, accQ);
                }
                Rsw[p][a] = accR;
                vmax[p] = (a == 0) ? accQ : fmaxf(vmax[p], accQ);
            }
        }
        #pragma unroll
        for (int p = 0; p < 4; ++p)
            vpool[0 * VSTR + (row + 1) * VROW + (cb + p + 1)] = vmax[p];
    }
    __syncthreads();

    // ---- K-1 shared-weight VI steps, double-buffered v ----
    int cur = 0;
    for (int it = 0; it < K - 1; ++it) {
        const float* vb = &vpool[cur * VSTR + row * VROW + cb];
        float vwin[3][6];
        #pragma unroll
        for (int i = 0; i < 3; ++i)
            #pragma unroll
            for (int j = 0; j < 6; ++j) vwin[i][j] = vb[i * VROW + j];
        int nxt = cur ^ 1;
        float vmax[4];
        #pragma unroll
        for (int a = 0; a < 10; ++a) {
            #pragma unroll
            for (int p = 0; p < 4; ++p) {
                float acc = Rsw[p][a];
                #pragma unroll
                for (int d = 0; d < 9; ++d)
                    acc = fmaf(w_sw[d * 20 + 10 + a], vwin[d / 3][p + d % 3], acc);
                vmax[p] = (a == 0) ? acc : fmaxf(vmax[p], acc);
            }
        }
        #pragma unroll
        for (int p = 0; p < 4; ++p)
            vpool[nxt * VSTR + (row + 1) * VROW + (cb + p + 1)] = vmax[p];
        cur = nxt;
        __syncthreads();
    }

    // ---- final step with w_sw2: q -> global, gather (S1,S2) ----
    const int s1 = S1[b], s2 = S2[b];
    {
        float rwin[3][6], vwin[3][6];
        #pragma unroll
        for (int i = 0; i < 3; ++i) {
            const float* rp = &rs[(row + i) * VROW + cb];
            const float* vb = &vpool[cur * VSTR + (row + i) * VROW + cb];
            #pragma unroll
            for (int j = 0; j < 6; ++j) { rwin[i][j] = rp[j]; vwin[i][j] = vb[j]; }
        }
        float qv[4][10];
        #pragma unroll
        for (int a = 0; a < 10; ++a) {
            #pragma unroll
            for (int p = 0; p < 4; ++p) {
                float acc = 0.f;
                #pragma unroll
                for (int d = 0; d < 9; ++d) {
                    acc = fmaf(w_sw2[d * 20 + a],      rwin[d / 3][p + d % 3], acc);
                    acc = fmaf(w_sw2[d * 20 + 10 + a], vwin[d / 3][p + d % 3], acc);
                }
                qv[p][a] = acc;
            }
        }
        #pragma unroll
        for (int p = 0; p < 4; ++p) {
            float* qp = out + 2048 + ((size_t)((b * 64 + row) * 64 + cb + p)) * 10;
            #pragma unroll
            for (int h2 = 0; h2 < 5; ++h2)
                ((float2*)qp)[h2] = make_float2(qv[p][h2 * 2], qv[p][h2 * 2 + 1]);
        }
        #pragma unroll
        for (int p = 0; p < 4; ++p)
            if (row == s1 && s2 == cb + p) {
                #pragma unroll
                for (int a = 0; a < 10; ++a) qsel[a] = qv[p][a];
            }
    }
    __syncthreads();

    // ---- dense + softmax (thread 0), q_out (threads 0..9) ----
    if (t == 0) {
        float logits[8];
        float m = -1e30f;
        #pragma unroll
        for (int j = 0; j < 8; ++j) {
            float s = 0.f;
            #pragma unroll
            for (int a = 0; a < 10; ++a) s += qsel[a] * w_dense[a * 8 + j];
            logits[j] = s;
            m = fmaxf(m, s);
        }
        float sum = 0.f;
        float e[8];
        #pragma unroll
        for (int j = 0; j < 8; ++j) { e[j] = expf(logits[j] - m); sum += e[j]; }
        float inv = 1.f / sum;
        #pragma unroll
        for (int j = 0; j < 8; ++j) {
            out[b * 8 + j] = logits[j];
            out[1024 + b * 8 + j] = e[j] * inv;
        }
    }
    if (t < 10) out[5244928 + b * 10 + t] = qsel[t];
}

extern "C" void kernel_launch(void* const* d_in, const int* in_sizes, int n_in,
                              void* d_out, int out_size, void* d_ws, size_t ws_size,
                              hipStream_t stream) {
    const float* x      = (const float*)d_in[0];
    const int*   S1     = (const int*)d_in[1];
    const int*   S2     = (const int*)d_in[2];
    const int*   VInum  = (const int*)d_in[3];
    const float* w0     = (const float*)d_in[4];
    const float* b0     = (const float*)d_in[5];
    const float* w_r    = (const float*)d_in[6];
    const float* w_q    = (const float*)d_in[7];
    const float* w_sw   = (const float*)d_in[8];
    const float* w_sw2  = (const float*)d_in[9];
    const float* w_dense= (const float*)d_in[10];
    float* out = (float*)d_out;

    vin_kernel<<<128, 1024, 0, stream>>>(x, S1, S2, VInum, w0, b0, w_r, w_q,
                                         w_sw, w_sw2, w_dense, out);
}

// Round 5
// 304.710 us; speedup vs baseline: 1.2600x; 1.2600x over previous
//
#include <hip/hip_runtime.h>
#include <math.h>

// VIN forward on MI355X — single fused kernel.
// Sizes: N=128, H=W=64, CH_I=2, CH_H=150, CH_Q=10, N_ACT=8, VInum=36.
//
// R4 -> R5 change (test the SGPR-starvation theory):
//  R4 proved VGPR pressure is NOT the issue (waves_per_eu(4,4) changed nothing;
//  allocator is content at 64). New theory: the 90 w_sw weights are
//  wave-uniform -> compiler keeps them as s_load-per-iteration (only ~102
//  SGPRs exist), and the s_load->v_fma latency chains are the ~12.6K cy/iter
//  stall. Fix: hold the weights in per-lane VGPRs. That needs ~215 live VGPRs,
//  impossible at 16 waves/CU, so:
//   * 512-thread WGs (8 waves/CU = 2 waves/EU -> 256-VGPR budget), 8 px/thread
//   * amdgpu_waves_per_eu(2,2) so the allocator uses the full budget
//   * w_sw v-part staged to LDS once, copied to float wv[90] register array
//     before the K-loop; all K-loop FMA operands are then VGPR-resident.

#define XROW 69
#define VROW 67
#define VSTR (66 * VROW)          // 4422 floats per v buffer

__global__ void
__attribute__((amdgpu_flat_work_group_size(512, 512)))
__attribute__((amdgpu_waves_per_eu(2, 2)))
vin_kernel(const float* __restrict__ x,
           const int* __restrict__ S1,
           const int* __restrict__ S2,
           const int* __restrict__ VInum,
           const float* __restrict__ w0,
           const float* __restrict__ b0,
           const float* __restrict__ w_r,
           const float* __restrict__ w_q,
           const float* __restrict__ w_sw,
           const float* __restrict__ w_sw2,
           const float* __restrict__ w_dense,
           float* __restrict__ out) {
    const int b = blockIdx.x;
    const int t = threadIdx.x;

    __shared__ float xs0[68 * XROW];     // x ch0, [y+2][x+2], 2-halo of zeros
    __shared__ float xs1[68 * XROW];     // x ch1
    __shared__ float rs[66 * VROW];      // r with 1-halo of zeros
    __shared__ float vpool[2 * VSTR];    // v double buffer, 1-halo of zeros
    __shared__ float wtmp[840];          // W5 partials [0..749], B partials [750..839]
    __shared__ float wfin[60];           // W5[50], B[9], Btot
    __shared__ float swv[90];            // w_sw v-part, [d][a]
    __shared__ float qsel[10];

    // ---- zero LDS (halos must be 0) ----
    for (int i = t; i < 68 * XROW; i += 512) { xs0[i] = 0.f; xs1[i] = 0.f; }
    for (int i = t; i < 66 * VROW; i += 512) rs[i] = 0.f;
    for (int i = t; i < 2 * VSTR; i += 512) vpool[i] = 0.f;
    if (t < 90) swv[t] = w_sw[(t / 10) * 20 + 10 + (t % 10)];
    __syncthreads();

    const int row = t >> 3;          // 0..63
    const int cb  = (t & 7) << 3;    // 0,8,...,56  (8 px per thread)

    // ---- stage x into split planes (16 contiguous floats = 4x float4) ----
    {
        const float* xb = x + (size_t)b * 64 * 64 * 2;
        const float4* xp = (const float4*)(xb + (row * 64 + cb) * 2);
        #pragma unroll
        for (int g = 0; g < 4; ++g) {
            float4 v4 = xp[g];
            int px = cb + g * 2;
            xs0[(row + 2) * XROW + px + 2] = v4.x;
            xs1[(row + 2) * XROW + px + 2] = v4.y;
            xs0[(row + 2) * XROW + px + 3] = v4.z;
            xs1[(row + 2) * XROW + px + 3] = v4.w;
        }
    }
    // ---- W5 compose partials: 50 entries x 15 channel-chunks (750 items) ----
    for (int w = t; w < 750; w += 512) {
        int e2 = w / 15, pi = w - e2 * 15;
        int e = e2 >> 1, ci = e2 & 1;
        int ey = e / 5 - 2, ex = e % 5 - 2;
        int c0 = pi * 10;
        float s = 0.f;
        for (int dqy = -1; dqy <= 1; ++dqy)
            for (int dqx = -1; dqx <= 1; ++dqx) {
                int dsy = ey - dqy, dsx = ex - dqx;
                if (dsy < -1 || dsy > 1 || dsx < -1 || dsx > 1) continue;
                const float* wr = w_r + ((dqy + 1) * 3 + (dqx + 1)) * 150;
                const float* wp = w0 + (((dsy + 1) * 3 + (dsx + 1)) * 2 + ci) * 150;
                for (int c = c0; c < c0 + 10; ++c) s += wr[c] * wp[c];
            }
        wtmp[w] = s;
    }
    if (t < 90) {
        int d = t / 10, pi = t - d * 10, c0 = pi * 15;
        float s = 0.f;
        for (int c = c0; c < c0 + 15; ++c) s += w_r[d * 150 + c] * b0[c];
        wtmp[750 + t] = s;
    }
    __syncthreads();
    if (t < 50) {
        float s = 0.f;
        for (int i = 0; i < 15; ++i) s += wtmp[t * 15 + i];
        wfin[t] = s;
    } else if (t < 59) {
        int d = t - 50;
        float s = 0.f;
        for (int i = 0; i < 10; ++i) s += wtmp[750 + d * 10 + i];
        wfin[t] = s;
    } else if (t == 59) {
        float s = 0.f;
        for (int j = 0; j < 90; ++j) s += wtmp[750 + j];
        wfin[59] = s;
    }
    __syncthreads();

    // ---- r interior via composed 5x5 conv ----
    {
        float W5a[25], W5b[25];
        #pragma unroll
        for (int e = 0; e < 25; ++e) { W5a[e] = wfin[e * 2]; W5b[e] = wfin[e * 2 + 1]; }
        float Btot = wfin[59];
        #pragma unroll
        for (int p = 0; p < 8; ++p) {
            int xx = cb + p;
            float acc = Btot;
            #pragma unroll
            for (int ey = 0; ey < 5; ++ey)
                #pragma unroll
                for (int ex = 0; ex < 5; ++ex) {
                    int xi = (row + ey) * XROW + (xx + ex);
                    acc = fmaf(xs0[xi], W5a[ey * 5 + ex], acc);
                    acc = fmaf(xs1[xi], W5b[ey * 5 + ex], acc);
                }
            rs[(row + 1) * VROW + (xx + 1)] = acc;
        }
    }
    __syncthreads();

    // ---- border fix: 260 virtual-h positions x 4 channel chunks = 1040 items ----
    for (int wi = t; wi < 1040; wi += 512) {
        int qi = wi >> 2, ch = wi & 3;
        int qy, qx;
        if (qi < 66)       { qy = -1; qx = qi - 1; }
        else if (qi < 132) { qy = 64; qx = qi - 67; }
        else if (qi < 196) { qx = -1; qy = qi - 132; }
        else               { qx = 64; qy = qi - 196; }
        int c0 = (ch < 2) ? ch * 38 : 76 + (ch - 2) * 37;
        int c1 = (ch < 2) ? c0 + 38 : c0 + 37;
        float sdq[9];
        #pragma unroll
        for (int d = 0; d < 9; ++d) sdq[d] = 0.f;
        for (int c = c0; c < c1; ++c) {
            float hc = 0.f;
            #pragma unroll
            for (int ky = 0; ky < 3; ++ky)
                #pragma unroll
                for (int kx = 0; kx < 3; ++kx) {
                    int xi = (qy + ky + 1) * XROW + (qx + kx + 1);
                    const float* wp = &w0[((ky * 3 + kx) * 2) * 150 + c];
                    hc = fmaf(xs0[xi], wp[0], hc);
                    hc = fmaf(xs1[xi], wp[150], hc);
                }
            #pragma unroll
            for (int d = 0; d < 9; ++d) sdq[d] = fmaf(w_r[d * 150 + c], hc, sdq[d]);
        }
        #pragma unroll
        for (int d = 0; d < 9; ++d) {
            int dy = d / 3 - 1, dx = d % 3 - 1;
            int py = qy - dy, px = qx - dx;
            if (py >= 0 && py < 64 && px >= 0 && px < 64) {
                float corr = sdq[d] + (ch == 0 ? wfin[50 + d] : 0.f);
                atomicAdd(&rs[(py + 1) * VROW + (px + 1)], -corr);
            }
        }
    }
    __syncthreads();

    const int K = VInum[0];

    // ---- Rsw precompute (loop-invariant r-part of w_sw conv) + first step (w_q) ----
    float Rsw[8][10];
    {
        float rwin[3][10];
        #pragma unroll
        for (int i = 0; i < 3; ++i) {
            const float* rp = &rs[(row + i) * VROW + cb];
            #pragma unroll
            for (int j = 0; j < 10; ++j) rwin[i][j] = rp[j];
        }
        float vmax[8];
        #pragma unroll
        for (int a = 0; a < 10; ++a) {
            #pragma unroll
            for (int p = 0; p < 8; ++p) {
                float accR = 0.f, accQ = 0.f;
                #pragma unroll
                for (int d = 0; d < 9; ++d) {
                    float rv = rwin[d / 3][p + d % 3];
                    accR = fmaf(w_sw[d * 20 + a], rv, accR);
                    accQ = fmaf(w_q[d * 20 + a],  rv, accQ);
                }
                Rsw[p][a] = accR;
                vmax[p] = (a == 0) ? accQ : fmaxf(vmax[p], accQ);
            }
        }
        #pragma unroll
        for (int p = 0; p < 8; ++p)
            vpool[0 * VSTR + (row + 1) * VROW + (cb + p + 1)] = vmax[p];
    }

    // ---- load w_sw v-part into per-lane VGPRs (the experiment) ----
    float wv[90];
    #pragma unroll
    for (int i = 0; i < 90; ++i) wv[i] = swv[i];
    __syncthreads();

    // ---- K-1 shared-weight VI steps, double-buffered v ----
    int cur = 0;
    for (int it = 0; it < K - 1; ++it) {
        const float* vb = &vpool[cur * VSTR + row * VROW + cb];
        float vwin[3][10];
        #pragma unroll
        for (int i = 0; i < 3; ++i)
            #pragma unroll
            for (int j = 0; j < 10; ++j) vwin[i][j] = vb[i * VROW + j];
        int nxt = cur ^ 1;
        float vmax[8];
        #pragma unroll
        for (int a = 0; a < 10; ++a) {
            #pragma unroll
            for (int p = 0; p < 8; ++p) {
                float acc = Rsw[p][a];
                #pragma unroll
                for (int d = 0; d < 9; ++d)
                    acc = fmaf(wv[d * 10 + a], vwin[d / 3][p + d % 3], acc);
                vmax[p] = (a == 0) ? acc : fmaxf(vmax[p], acc);
            }
        }
        #pragma unroll
        for (int p = 0; p < 8; ++p)
            vpool[nxt * VSTR + (row + 1) * VROW + (cb + p + 1)] = vmax[p];
        cur = nxt;
        __syncthreads();
    }

    // ---- final step with w_sw2: q -> global, gather (S1,S2) ----
    const int s1 = S1[b], s2 = S2[b];
    {
        float rwin[3][10], vwin[3][10];
        #pragma unroll
        for (int i = 0; i < 3; ++i) {
            const float* rp = &rs[(row + i) * VROW + cb];
            const float* vb = &vpool[cur * VSTR + (row + i) * VROW + cb];
            #pragma unroll
            for (int j = 0; j < 10; ++j) { rwin[i][j] = rp[j]; vwin[i][j] = vb[j]; }
        }
        float qv[8][10];
        #pragma unroll
        for (int a = 0; a < 10; ++a) {
            #pragma unroll
            for (int p = 0; p < 8; ++p) {
                float acc = 0.f;
                #pragma unroll
                for (int d = 0; d < 9; ++d) {
                    acc = fmaf(w_sw2[d * 20 + a],      rwin[d / 3][p + d % 3], acc);
                    acc = fmaf(w_sw2[d * 20 + 10 + a], vwin[d / 3][p + d % 3], acc);
                }
                qv[p][a] = acc;
            }
        }
        // store q: 80 contiguous floats (8 px x 10 actions), 16B-aligned
        {
            float4* qp4 = (float4*)(out + 2048 + ((size_t)((b * 64 + row) * 64 + cb)) * 10);
            #pragma unroll
            for (int g = 0; g < 20; ++g)
                qp4[g] = make_float4(qv[(g * 4) / 10][(g * 4) % 10],
                                     qv[(g * 4 + 1) / 10][(g * 4 + 1) % 10],
                                     qv[(g * 4 + 2) / 10][(g * 4 + 2) % 10],
                                     qv[(g * 4 + 3) / 10][(g * 4 + 3) % 10]);
        }
        if (row == s1) {
            #pragma unroll
            for (int p = 0; p < 8; ++p)
                if (s2 == cb + p) {
                    #pragma unroll
                    for (int a = 0; a < 10; ++a) qsel[a] = qv[p][a];
                }
        }
    }
    __syncthreads();

    // ---- dense + softmax (thread 0), q_out (threads 0..9) ----
    if (t == 0) {
        float logits[8];
        float m = -1e30f;
        #pragma unroll
        for (int j = 0; j < 8; ++j) {
            float s = 0.f;
            #pragma unroll
            for (int a = 0; a < 10; ++a) s += qsel[a] * w_dense[a * 8 + j];
            logits[j] = s;
            m = fmaxf(m, s);
        }
        float sum = 0.f;
        float e[8];
        #pragma unroll
        for (int j = 0; j < 8; ++j) { e[j] = expf(logits[j] - m); sum += e[j]; }
        float inv = 1.f / sum;
        #pragma unroll
        for (int j = 0; j < 8; ++j) {
            out[b * 8 + j] = logits[j];
            out[1024 + b * 8 + j] = e[j] * inv;
        }
    }
    if (t < 10) out[5244928 + b * 10 + t] = qsel[t];
}

extern "C" void kernel_launch(void* const* d_in, const int* in_sizes, int n_in,
                              void* d_out, int out_size, void* d_ws, size_t ws_size,
                              hipStream_t stream) {
    const float* x      = (const float*)d_in[0];
    const int*   S1     = (const int*)d_in[1];
    const int*   S2     = (const int*)d_in[2];
    const int*   VInum  = (const int*)d_in[3];
    const float* w0     = (const float*)d_in[4];
    const float* b0     = (const float*)d_in[5];
    const float* w_r    = (const float*)d_in[6];
    const float* w_q    = (const float*)d_in[7];
    const float* w_sw   = (const float*)d_in[8];
    const float* w_sw2  = (const float*)d_in[9];
    const float* w_dense= (const float*)d_in[10];
    float* out = (float*)d_out;

    vin_kernel<<<128, 512, 0, stream>>>(x, S1, S2, VInum, w0, b0, w_r, w_q,
                                        w_sw, w_sw2, w_dense, out);
}